// Round 1
// baseline (97.842 us; speedup 1.0000x reference)
//
#include <hip/hip_runtime.h>

#define NQ 14
#define NSTATE (1 << NQ)
// state (16384 float2) + Btab (28 float2) + rx3c/s (14+14) + xx2c/s (7+7)
#define SMEM_BYTES (NSTATE*8 + 28*8 + 28*4 + 14*4)

__device__ __forceinline__ float2 cmulf(float2 a, float2 b){
    return make_float2(a.x*b.x - a.y*b.y, a.x*b.y + a.y*b.x);
}

// Apply [[c, -i*sn], [-i*sn, c]] to the (A,B) pair (RX gate / XX coupled pair)
__device__ __forceinline__ void rot2(float2& A, float2& B, float c, float sn){
    float2 a = A, b = B;
    A = make_float2(fmaf(c, a.x,  sn*b.y), fmaf(c, a.y, -sn*b.x));
    B = make_float2(fmaf(c, b.x,  sn*a.y), fmaf(c, b.y, -sn*a.x));
}

// bank-conflict swizzle: amplitude i lives at LDS slot sigma(i); involution
__device__ __forceinline__ int slotof(int i){ return i ^ ((i >> 5) & 31); }

// Two XX gates (L bits 3,2 and L bits 1,0) + four RX gates (wires w0..w0+3 on L bits 3..0)
__device__ __forceinline__ void gates16(float2 amp[16], float c0, float s0, float c1, float s1,
                                        const float* rc, const float* rs, int w0)
{
    #pragma unroll
    for (int lo = 0; lo < 4; ++lo) { rot2(amp[lo], amp[lo|12], c0, s0); rot2(amp[lo|4], amp[lo|8], c0, s0); }
    #pragma unroll
    for (int hi = 0; hi < 16; hi += 4) { rot2(amp[hi], amp[hi|3], c1, s1); rot2(amp[hi|1], amp[hi|2], c1, s1); }
    #pragma unroll
    for (int j = 0; j < 4; ++j) {
        const int bm = 1 << (3 - j);
        const float c = rc[w0 + j], s = rs[w0 + j];
        #pragma unroll
        for (int L = 0; L < 16; ++L)
            if (!(L & bm)) rot2(amp[L], amp[L | bm], c, s);
    }
}

__global__ void __launch_bounds__(1024)
qsim_kernel(const float* __restrict__ cp, const float* __restrict__ p,
            float* __restrict__ out)
{
    extern __shared__ __align__(16) char smem[];
    float2* st   = reinterpret_cast<float2*>(smem);
    float2* Btab = reinterpret_cast<float2*>(smem + NSTATE*8);
    float*  rx3c = reinterpret_cast<float*>(smem + NSTATE*8 + 28*8);
    float*  rx3s = rx3c + 14;
    float*  xx2c = rx3s + 14;
    float*  xx2s = xx2c + 7;

    const int b = blockIdx.x;
    const int t = threadIdx.x;
    const float* pb  = p  + b * 42;   // p[b][3][14]
    const float* cpb = cp + b * 14;   // cp[b][14]

    // ---- per-block tables (RX1 x XX1 x RZ fused into 7 two-qubit blocks) ----
    if (t < 7) {
        const int ws = t, wa = 2*ws, wb = 2*ws + 1;
        float sa, ca; sincosf(0.5f * pb[wa], &sa, &ca);
        float sb, cb; sincosf(0.5f * pb[wb], &sb, &cb);
        // after RX(alpha)⊗RX(beta) on |00>
        float2 s00 = make_float2(ca*cb, 0.f);
        float2 s01 = make_float2(0.f, -ca*sb);
        float2 s10 = make_float2(0.f, -sa*cb);
        float2 s11 = make_float2(-sa*sb, 0.f);
        // IsingXX(cp[ws]) couples 00<->11, 01<->10
        float sx, cx; sincosf(0.5f * cpb[ws], &sx, &cx);
        rot2(s00, s11, cx, sx);
        rot2(s01, s10, cx, sx);
        // RZ on both wires: phase exp(i*0.5*(±ga ±gb)), + if bit=1
        const float ga = 0.5f * pb[14 + wa], gb = 0.5f * pb[14 + wb];
        float sA, cA; sincosf(ga + gb, &sA, &cA);
        float sB, cB; sincosf(gb - ga, &sB, &cB);
        s00 = cmulf(s00, make_float2(cA, -sA));
        s11 = cmulf(s11, make_float2(cA,  sA));
        s01 = cmulf(s01, make_float2(cB,  sB));
        s10 = cmulf(s10, make_float2(cB, -sB));
        const int k = 6 - ws;                 // crumb k = index bits (2k+1,2k)
        Btab[k*4+0] = s00; Btab[k*4+1] = s01; Btab[k*4+2] = s10; Btab[k*4+3] = s11;
    } else if (t >= 64 && t < 78) {
        const int w = t - 64;
        float s, c; sincosf(0.5f * pb[28 + w], &s, &c);
        rx3c[w] = c; rx3s[w] = s;
    } else if (t >= 128 && t < 135) {
        const int g = t - 128;
        float s, c; sincosf(0.5f * cpb[7 + g], &s, &c);
        xx2c[g] = c; xx2s[g] = s;
    }
    __syncthreads();

    float2 amp[16];

    // ---- Pass A: build product state + XX(1,2), XX(3,4) + RX3 wires 1..4 (bits 12..9 local)
    {
        const int ibase = (t & 0x1FF) | ((t >> 9) << 13);   // bits 0-8, 13 from thread
        float2 Pc = cmulf(cmulf(Btab[(ibase & 3)],            Btab[4  + ((ibase >> 2) & 3)]),
                          cmulf(Btab[8 + ((ibase >> 4) & 3)], Btab[12 + ((ibase >> 6) & 3)]));
        const int b8  = (ibase >> 8) & 1;
        const int b13 = (ibase >> 13) & 1;
        #pragma unroll
        for (int L = 0; L < 16; ++L) {                       // L bit j -> index bit 9+j
            const int c4 = ((L & 1) << 1) | b8;              // bits (9,8)
            const int c5 = (L >> 1) & 3;                     // bits (11,10)
            const int c6 = (b13 << 1) | ((L >> 3) & 1);      // bits (13,12)
            amp[L] = cmulf(cmulf(Pc, Btab[16 + c4]), cmulf(Btab[20 + c5], Btab[24 + c6]));
        }
        gates16(amp, xx2c[0], xx2s[0], xx2c[1], xx2s[1], rx3c, rx3s, 1);
        #pragma unroll
        for (int L = 0; L < 16; ++L) st[slotof(ibase | (L << 9))] = amp[L];
    }
    __syncthreads();

    // ---- Pass B: XX(5,6), XX(7,8) + RX3 wires 5..8 (bits 8..5 local)
    {
        const int ibase = (t & 31) | ((t >> 5) << 9);
        #pragma unroll
        for (int L = 0; L < 16; ++L) amp[L] = st[slotof(ibase | (L << 5))];
        gates16(amp, xx2c[2], xx2s[2], xx2c[3], xx2s[3], rx3c, rx3s, 5);
        #pragma unroll
        for (int L = 0; L < 16; ++L) st[slotof(ibase | (L << 5))] = amp[L];
    }
    __syncthreads();

    // ---- Pass C: XX(9,10), XX(11,12) + RX3 wires 9..12 (bits 4..1 local)
    {
        const int ibase = (t & 1) | ((t >> 1) << 5);
        #pragma unroll
        for (int L = 0; L < 16; ++L) amp[L] = st[slotof(ibase | (L << 1))];
        gates16(amp, xx2c[4], xx2s[4], xx2c[5], xx2s[5], rx3c, rx3s, 9);
        #pragma unroll
        for (int L = 0; L < 16; ++L) st[slotof(ibase | (L << 1))] = amp[L];
    }
    __syncthreads();

    // ---- Pass D: XX(13,0) + RX3 wires 13, 0 (bits 0 and 13 local; bits 1,2 filler)
    {
        const int tb = t << 3;   // thread bits -> index bits 3..12
        #pragma unroll
        for (int L = 0; L < 16; ++L) {
            const int i = tb | (L & 1) | (((L >> 1) & 1) << 13) | (((L >> 2) & 1) << 1) | (((L >> 3) & 1) << 2);
            amp[L] = st[slotof(i)];
        }
        {   // XX on (wire13 = L bit0, wire0 = L bit1)
            const float c = xx2c[6], s = xx2s[6];
            #pragma unroll
            for (int f = 0; f < 16; f += 4) { rot2(amp[f], amp[f|3], c, s); rot2(amp[f|1], amp[f|2], c, s); }
        }
        {   // RX wire 13 (L bit0)
            const float c = rx3c[13], s = rx3s[13];
            #pragma unroll
            for (int L = 0; L < 16; ++L) if (!(L & 1)) rot2(amp[L], amp[L|1], c, s);
        }
        {   // RX wire 0 (L bit1)
            const float c = rx3c[0], s = rx3s[0];
            #pragma unroll
            for (int L = 0; L < 16; ++L) if (!(L & 2)) rot2(amp[L], amp[L|2], c, s);
        }
        #pragma unroll
        for (int L = 0; L < 16; ++L) {
            const int i = tb | (L & 1) | (((L >> 1) & 1) << 13) | (((L >> 2) & 1) << 1) | (((L >> 3) & 1) << 2);
            st[slotof(i)] = amp[L];
        }
    }
    __syncthreads();

    // ---- Pass E: MCX perms as composed index map + Z-sign accumulate + reduce
    float acc[NQ];
    #pragma unroll
    for (int w = 0; w < NQ; ++w) acc[w] = 0.f;
    #pragma unroll
    for (int k = 0; k < 16; ++k) {
        const int s = t | (k << 10);
        const float2 a = st[s];
        const float pr = fmaf(a.x, a.x, a.y * a.y);
        int x = slotof(s);                 // amplitude index j held at slot s
        // i = P13(P12(...P0(j))) : inverse of the applied permutation chain
        #pragma unroll
        for (int w = 0; w < NQ; ++w) {
            const int p1 = 13 - w;
            const int p2 = 13 - ((w + 1) % NQ);
            const int pt = 13 - ((w + 2) % NQ);
            const int cond = ((x >> p1) & ~(x >> p2)) & 1;
            x ^= (cond << pt);
        }
        const unsigned pu = __float_as_uint(pr);
        #pragma unroll
        for (int w = 0; w < NQ; ++w) {
            const unsigned sg = (((unsigned)x) << (18 + w)) & 0x80000000u;  // bit(13-w) -> sign
            acc[w] += __uint_as_float(pu ^ sg);
        }
    }
    // wave reduction (64 lanes)
    #pragma unroll
    for (int w = 0; w < NQ; ++w) {
        float v = acc[w];
        v += __shfl_down(v, 32);
        v += __shfl_down(v, 16);
        v += __shfl_down(v, 8);
        v += __shfl_down(v, 4);
        v += __shfl_down(v, 2);
        v += __shfl_down(v, 1);
        acc[w] = v;
    }
    __syncthreads();                      // all st reads done; reuse LDS as scratch
    float* red = reinterpret_cast<float*>(smem);
    if ((t & 63) == 0) {
        const int wv = t >> 6;
        #pragma unroll
        for (int w = 0; w < NQ; ++w) red[wv * NQ + w] = acc[w];
    }
    __syncthreads();
    if (t < NQ) {
        float ssum = 0.f;
        #pragma unroll
        for (int wv = 0; wv < 16; ++wv) ssum += red[wv * NQ + t];
        out[b * NQ + t] = ssum;
    }
}

extern "C" void kernel_launch(void* const* d_in, const int* in_sizes, int n_in,
                              void* d_out, int out_size, void* d_ws, size_t ws_size,
                              hipStream_t stream)
{
    (void)n_in; (void)out_size; (void)d_ws; (void)ws_size;
    const float* cp = (const float*)d_in[0];
    const float* p  = (const float*)d_in[1];
    float* out = (float*)d_out;
    const int B = in_sizes[0] / NQ;   // 512
    (void)hipFuncSetAttribute(reinterpret_cast<const void*>(qsim_kernel),
                              hipFuncAttributeMaxDynamicSharedMemorySize, SMEM_BYTES);
    qsim_kernel<<<B, 1024, SMEM_BYTES, stream>>>(cp, p, out);
}

// Round 3
// 84.403 us; speedup vs baseline: 1.1592x; 1.1592x over previous
//
#include <hip/hip_runtime.h>

#define NQ 14
#define NSTATE (1 << NQ)
// state (16384 float2) + Btab (28 float2) + rx3c/s (14+14) + xx2c/s (7+7) + red (16*14 f32)
#define OFF_BTAB  (NSTATE*8)
#define OFF_RX3   (OFF_BTAB + 28*8)
#define OFF_XX2   (OFF_RX3 + 28*4)
#define OFF_RED   (OFF_XX2 + 14*4)
#define SMEM_BYTES (OFF_RED + 16*NQ*4)

__device__ __forceinline__ float2 cmulf(float2 a, float2 b){
    return make_float2(a.x*b.x - a.y*b.y, a.x*b.y + a.y*b.x);
}

// Apply [[c, -i*sn], [-i*sn, c]] to the (A,B) pair (RX gate / XX coupled pair)
__device__ __forceinline__ void rot2(float2& A, float2& B, float c, float sn){
    float2 a = A, b = B;
    A = make_float2(fmaf(c, a.x,  sn*b.y), fmaf(c, a.y, -sn*b.x));
    B = make_float2(fmaf(c, b.x,  sn*a.y), fmaf(c, b.y, -sn*a.x));
}

// bank-conflict swizzle: amplitude i lives at LDS slot sigma(i); involution
__device__ __forceinline__ int slotof(int i){ return i ^ ((i >> 5) & 31); }

// Two XX gates (L bits 3,2 and L bits 1,0) + four RX gates (wires w0..w0+3 on L bits 3..0)
__device__ __forceinline__ void gates16(float2 amp[16], float c0, float s0, float c1, float s1,
                                        const float* rc, const float* rs, int w0)
{
    #pragma unroll
    for (int lo = 0; lo < 4; ++lo) { rot2(amp[lo], amp[lo|12], c0, s0); rot2(amp[lo|4], amp[lo|8], c0, s0); }
    #pragma unroll
    for (int hi = 0; hi < 16; hi += 4) { rot2(amp[hi], amp[hi|3], c1, s1); rot2(amp[hi|1], amp[hi|2], c1, s1); }
    #pragma unroll
    for (int j = 0; j < 4; ++j) {
        const int bm = 1 << (3 - j);
        const float c = rc[w0 + j], s = rs[w0 + j];
        #pragma unroll
        for (int L = 0; L < 16; ++L)
            if (!(L & bm)) rot2(amp[L], amp[L | bm], c, s);
    }
}

// ---- pre-kernel: composed inverse MCX chain -> gather table (SLOT INDEX, incl. swizzle).
// For final index i, source amp j = pi_0(pi_1(...pi_13(i))) (each pi_w an involution).
// Layout transposed for per-thread-contiguous loads: tbl[(i&1023)*16 + (i>>10)].
// NOTE: stores slot index (0..16383, fits u16) -- NOT byte offset (would overflow u16).
__global__ void perm_tbl_kernel(unsigned short* __restrict__ tbl)
{
    const int i = blockIdx.x * blockDim.x + threadIdx.x;   // 0..16383
    int x = i;
    #pragma unroll
    for (int w = 13; w >= 0; --w) {
        const int p1 = 13 - w;
        const int p2 = 13 - ((w + 1) % NQ);
        const int pt = 13 - ((w + 2) % NQ);
        const int cond = ((x >> p1) & ~(x >> p2)) & 1;
        x ^= cond << pt;
    }
    const int slot = x ^ ((x >> 5) & 31);
    tbl[(i & 1023) * 16 + (i >> 10)] = (unsigned short)slot;
}

__global__ void __launch_bounds__(1024)
qsim_kernel(const float* __restrict__ cp, const float* __restrict__ p,
            const unsigned short* __restrict__ tbl, float* __restrict__ out)
{
    extern __shared__ __align__(16) char smem[];
    float2* st   = reinterpret_cast<float2*>(smem);
    float2* Btab = reinterpret_cast<float2*>(smem + OFF_BTAB);
    float*  rx3c = reinterpret_cast<float*>(smem + OFF_RX3);
    float*  rx3s = rx3c + 14;
    float*  xx2c = reinterpret_cast<float*>(smem + OFF_XX2);
    float*  xx2s = xx2c + 7;
    float*  red  = reinterpret_cast<float*>(smem + OFF_RED);

    const int b = blockIdx.x;
    const int t = threadIdx.x;
    const float* pb  = p  + b * 42;   // p[b][3][14]
    const float* cpb = cp + b * 14;   // cp[b][14]

    // ---- per-block tables (RX1 x XX1 x RZ fused into 7 two-qubit blocks) ----
    if (t < 7) {
        const int ws = t, wa = 2*ws, wb = 2*ws + 1;
        float sa, ca; sincosf(0.5f * pb[wa], &sa, &ca);
        float sb, cb; sincosf(0.5f * pb[wb], &sb, &cb);
        float2 s00 = make_float2(ca*cb, 0.f);
        float2 s01 = make_float2(0.f, -ca*sb);
        float2 s10 = make_float2(0.f, -sa*cb);
        float2 s11 = make_float2(-sa*sb, 0.f);
        float sx, cx; sincosf(0.5f * cpb[ws], &sx, &cx);
        rot2(s00, s11, cx, sx);
        rot2(s01, s10, cx, sx);
        const float ga = 0.5f * pb[14 + wa], gb = 0.5f * pb[14 + wb];
        float sA, cA; sincosf(ga + gb, &sA, &cA);
        float sB, cB; sincosf(gb - ga, &sB, &cB);
        s00 = cmulf(s00, make_float2(cA, -sA));
        s11 = cmulf(s11, make_float2(cA,  sA));
        s01 = cmulf(s01, make_float2(cB,  sB));
        s10 = cmulf(s10, make_float2(cB, -sB));
        const int k = 6 - ws;                 // crumb k = index bits (2k+1,2k)
        Btab[k*4+0] = s00; Btab[k*4+1] = s01; Btab[k*4+2] = s10; Btab[k*4+3] = s11;
    } else if (t >= 64 && t < 78) {
        const int w = t - 64;
        float s, c; sincosf(0.5f * pb[28 + w], &s, &c);
        rx3c[w] = c; rx3s[w] = s;
    } else if (t >= 128 && t < 135) {
        const int g = t - 128;
        float s, c; sincosf(0.5f * cpb[7 + g], &s, &c);
        xx2c[g] = c; xx2s[g] = s;
    }
    __syncthreads();

    float2 amp[16];

    // ---- Pass A: build product state + XX(1,2), XX(3,4) + RX3 wires 1..4 (bits 12..9 local)
    {
        const int ibase = (t & 0x1FF) | ((t >> 9) << 13);   // bits 0-8, 13 from thread
        float2 Pc = cmulf(cmulf(Btab[(ibase & 3)],            Btab[4  + ((ibase >> 2) & 3)]),
                          cmulf(Btab[8 + ((ibase >> 4) & 3)], Btab[12 + ((ibase >> 6) & 3)]));
        const int b8  = (ibase >> 8) & 1;
        const int b13 = (ibase >> 13) & 1;
        #pragma unroll
        for (int L = 0; L < 16; ++L) {                       // L bit j -> index bit 9+j
            const int c4 = ((L & 1) << 1) | b8;              // bits (9,8)
            const int c5 = (L >> 1) & 3;                     // bits (11,10)
            const int c6 = (b13 << 1) | ((L >> 3) & 1);      // bits (13,12)
            amp[L] = cmulf(cmulf(Pc, Btab[16 + c4]), cmulf(Btab[20 + c5], Btab[24 + c6]));
        }
        gates16(amp, xx2c[0], xx2s[0], xx2c[1], xx2s[1], rx3c, rx3s, 1);
        #pragma unroll
        for (int L = 0; L < 16; ++L) st[slotof(ibase | (L << 9))] = amp[L];
    }
    __syncthreads();

    // ---- Pass B: XX(5,6), XX(7,8) + RX3 wires 5..8 (bits 8..5 local)
    {
        const int ibase = (t & 31) | ((t >> 5) << 9);
        #pragma unroll
        for (int L = 0; L < 16; ++L) amp[L] = st[slotof(ibase | (L << 5))];
        gates16(amp, xx2c[2], xx2s[2], xx2c[3], xx2s[3], rx3c, rx3s, 5);
        #pragma unroll
        for (int L = 0; L < 16; ++L) st[slotof(ibase | (L << 5))] = amp[L];
    }
    __syncthreads();

    // ---- Pass C: XX(9,10), XX(11,12) + RX3 wires 9..12 (bits 4..1 local)
    {
        const int ibase = (t & 1) | ((t >> 1) << 5);
        #pragma unroll
        for (int L = 0; L < 16; ++L) amp[L] = st[slotof(ibase | (L << 1))];
        gates16(amp, xx2c[4], xx2s[4], xx2c[5], xx2s[5], rx3c, rx3s, 9);
        #pragma unroll
        for (int L = 0; L < 16; ++L) st[slotof(ibase | (L << 1))] = amp[L];
    }
    __syncthreads();

    // ---- Pass D: XX(13,0) + RX3 wires 13, 0 (bits 0 and 13 local; bits 1,2 filler)
    {
        const int tb = t << 3;   // thread bits -> index bits 3..12
        #pragma unroll
        for (int L = 0; L < 16; ++L) {
            const int i = tb | (L & 1) | (((L >> 1) & 1) << 13) | (((L >> 2) & 1) << 1) | (((L >> 3) & 1) << 2);
            amp[L] = st[slotof(i)];
        }
        {   // XX on (wire13 = L bit0, wire0 = L bit1)
            const float c = xx2c[6], s = xx2s[6];
            #pragma unroll
            for (int f = 0; f < 16; f += 4) { rot2(amp[f], amp[f|3], c, s); rot2(amp[f|1], amp[f|2], c, s); }
        }
        {   // RX wire 13 (L bit0)
            const float c = rx3c[13], s = rx3s[13];
            #pragma unroll
            for (int L = 0; L < 16; ++L) if (!(L & 1)) rot2(amp[L], amp[L|1], c, s);
        }
        {   // RX wire 0 (L bit1)
            const float c = rx3c[0], s = rx3s[0];
            #pragma unroll
            for (int L = 0; L < 16; ++L) if (!(L & 2)) rot2(amp[L], amp[L|2], c, s);
        }
        #pragma unroll
        for (int L = 0; L < 16; ++L) {
            const int i = tb | (L & 1) | (((L >> 1) & 1) << 13) | (((L >> 2) & 1) << 1) | (((L >> 3) & 1) << 2);
            st[slotof(i)] = amp[L];
        }
    }
    __syncthreads();

    // ---- Pass E: table-driven gather over FINAL indices i = t | k<<10.
    // q[i] = |st[tbl[i]]|^2. Wire w <-> i bit (13-w):
    //   wires 0..3  <-> k bits 3..0  (compile-time signs in the unroll -> T - 2*U)
    //   wires 4..7  <-> wave bits 3..0 (wave-uniform sign of total S)
    //   wires 8..13 <-> lane bits 5..0 (sign-tracking shuffle butterfly)
    {
        // per-thread contiguous 32B of table: 16 slot indices
        unsigned off[16];
        {
            const uint4* tp = reinterpret_cast<const uint4*>(tbl + t * 16);
            const uint4 w0 = tp[0], w1 = tp[1];
            off[0]=w0.x&0xffffu; off[1]=w0.x>>16; off[2]=w0.y&0xffffu; off[3]=w0.y>>16;
            off[4]=w0.z&0xffffu; off[5]=w0.z>>16; off[6]=w0.w&0xffffu; off[7]=w0.w>>16;
            off[8]=w1.x&0xffffu; off[9]=w1.x>>16; off[10]=w1.y&0xffffu; off[11]=w1.y>>16;
            off[12]=w1.z&0xffffu; off[13]=w1.z>>16; off[14]=w1.w&0xffffu; off[15]=w1.w>>16;
        }
        float T = 0.f, U0 = 0.f, U1 = 0.f, U2 = 0.f, U3 = 0.f;
        #pragma unroll
        for (int k = 0; k < 16; ++k) {
            const float2 a = st[off[k]];
            const float q = fmaf(a.x, a.x, a.y * a.y);
            T += q;
            if (k & 1) U0 += q;   // i bit10 -> wire 3
            if (k & 2) U1 += q;   // i bit11 -> wire 2
            if (k & 4) U2 += q;   // i bit12 -> wire 1
            if (k & 8) U3 += q;   // i bit13 -> wire 0
        }
        // sign-tracking butterfly over 6 lane bits: s = sum(T), d[b] = sum(sigma_b(lane)*T)
        // (signs are only valid at lane 0, which is the lane that writes)
        float s = T;
        float d0, d1, d2, d3, d4, d5;
        {
            float o;
            o = __shfl_xor(s, 1);  d0 = s - o; s += o;
            o = __shfl_xor(d0, 2); d0 += o;
            o = __shfl_xor(s, 2);  d1 = s - o; s += o;
            o = __shfl_xor(d0, 4); d0 += o;
            o = __shfl_xor(d1, 4); d1 += o;
            o = __shfl_xor(s, 4);  d2 = s - o; s += o;
            o = __shfl_xor(d0, 8); d0 += o;
            o = __shfl_xor(d1, 8); d1 += o;
            o = __shfl_xor(d2, 8); d2 += o;
            o = __shfl_xor(s, 8);  d3 = s - o; s += o;
            o = __shfl_xor(d0, 16); d0 += o;
            o = __shfl_xor(d1, 16); d1 += o;
            o = __shfl_xor(d2, 16); d2 += o;
            o = __shfl_xor(d3, 16); d3 += o;
            o = __shfl_xor(s, 16);  d4 = s - o; s += o;
            o = __shfl_xor(d0, 32); d0 += o;
            o = __shfl_xor(d1, 32); d1 += o;
            o = __shfl_xor(d2, 32); d2 += o;
            o = __shfl_xor(d3, 32); d3 += o;
            o = __shfl_xor(d4, 32); d4 += o;
            o = __shfl_xor(s, 32);  d5 = s - o; s += o;
        }
        // plain lane reduction of the U's
        #pragma unroll
        for (int m = 1; m < 64; m <<= 1) {
            U0 += __shfl_xor(U0, m);
            U1 += __shfl_xor(U1, m);
            U2 += __shfl_xor(U2, m);
            U3 += __shfl_xor(U3, m);
        }
        if ((t & 63) == 0) {
            const int v = t >> 6;          // wave index = i bits 9..6
            float* r = red + v * NQ;
            r[0]  = s - 2.f * U3;
            r[1]  = s - 2.f * U2;
            r[2]  = s - 2.f * U1;
            r[3]  = s - 2.f * U0;
            r[4]  = (v & 8) ? -s : s;      // i bit9
            r[5]  = (v & 4) ? -s : s;      // i bit8
            r[6]  = (v & 2) ? -s : s;      // i bit7
            r[7]  = (v & 1) ? -s : s;      // i bit6
            r[8]  = d5;                    // i bit5
            r[9]  = d4;
            r[10] = d3;
            r[11] = d2;
            r[12] = d1;
            r[13] = d0;                    // i bit0 -> wire 13
        }
    }
    __syncthreads();
    if (t < NQ) {
        float ssum = 0.f;
        #pragma unroll
        for (int wv = 0; wv < 16; ++wv) ssum += red[wv * NQ + t];
        out[b * NQ + t] = ssum;
    }
}

extern "C" void kernel_launch(void* const* d_in, const int* in_sizes, int n_in,
                              void* d_out, int out_size, void* d_ws, size_t ws_size,
                              hipStream_t stream)
{
    (void)n_in; (void)out_size; (void)ws_size;
    const float* cp = (const float*)d_in[0];
    const float* p  = (const float*)d_in[1];
    float* out = (float*)d_out;
    unsigned short* tbl = (unsigned short*)d_ws;        // 32 KiB
    const int B = in_sizes[0] / NQ;   // 512

    perm_tbl_kernel<<<NSTATE / 256, 256, 0, stream>>>(tbl);

    (void)hipFuncSetAttribute(reinterpret_cast<const void*>(qsim_kernel),
                              hipFuncAttributeMaxDynamicSharedMemorySize, SMEM_BYTES);
    qsim_kernel<<<B, 1024, SMEM_BYTES, stream>>>(cp, p, tbl, out);
}